// Round 15
// baseline (128.671 us; speedup 1.0000x reference)
//
#include <hip/hip_runtime.h>

// LinearAttentionCell: chunked linear attention, bf16 MFMA.
// R15 = R14 + x-cast fused into proj (fp32 A reg-staging with in-register
// RNE bf16 convert -> swizzled ds_write). Deletes the 150MB cast pass.

constexpr int Bn  = 8;
constexpr int Sn  = 2048;
constexpr int Cn  = 512;
constexpr int Tn  = 128;
constexpr int NCn = 16;
constexpr float DKf = 0.04419417382415922f;     // 1/sqrt(512)

typedef __attribute__((ext_vector_type(8))) short bf16x8;
typedef __attribute__((ext_vector_type(4))) float f32x4;

__device__ __forceinline__ unsigned short f2bf(float f) {   // RNE
  unsigned u = __float_as_uint(f);
  u = (u + 0x7fffu + ((u >> 16) & 1u)) >> 16;
  return (unsigned short)u;
}
__device__ __forceinline__ float bf2f(unsigned short h) {
  return __uint_as_float(((unsigned)h) << 16);
}
__device__ __forceinline__ float phi_f(float u) {
  float s = u * DKf;
  return s > 0.0f ? s + 1.0f : __expf(s);       // elu(s)+1
}
__device__ __forceinline__ uint4 pack8(const float4 a, const float4 b) {
  uint4 o;
  o.x = (unsigned)f2bf(a.x) | ((unsigned)f2bf(a.y) << 16);
  o.y = (unsigned)f2bf(a.z) | ((unsigned)f2bf(a.w) << 16);
  o.z = (unsigned)f2bf(b.x) | ((unsigned)f2bf(b.y) << 16);
  o.w = (unsigned)f2bf(b.z) | ((unsigned)f2bf(b.w) << 16);
  return o;
}

// ---------------- W cast: {Wq,Wk,Wv} -> Wb (bf16) ----------------------------
__global__ __launch_bounds__(256) void k_castw(
    const float* __restrict__ Wq, const float* __restrict__ Wk,
    const float* __restrict__ Wv, unsigned short* __restrict__ Wb)
{
  const size_t f = ((size_t)blockIdx.x * 256 + threadIdx.x) * 8;
  const int z = (int)(f >> 18);                    // / (512*512)
  const float* __restrict__ src = (z == 0) ? Wq : (z == 1 ? Wk : Wv);
  const size_t i8 = f & ((1u << 18) - 1);
  float4 a = *(const float4*)&src[i8];
  float4 b = *(const float4*)&src[i8 + 4];
  *(uint4*)&Wb[((size_t)z << 18) + i8] = pack8(a, b);
}

// ---- stage a 128x64 bf16 tile global->LDS (256 thr, 4 issues/thread) --------
// 8 slots of 16B per row; swizzle slot ^= row&7 (8-row period, conflict-free).
__device__ __forceinline__ void stage128x64(const unsigned short* __restrict__ g,
                                            int ld, unsigned short* lds,
                                            int wid, int lane) {
#pragma unroll
  for (int e = 0; e < 4; ++e) {
    const int row = e * 32 + wid * 8 + (lane >> 3);
    const int ks  = (lane & 7) ^ (row & 7);
    const unsigned short* src = g + (size_t)row * ld + ks * 8;
    unsigned short* dst = lds + (size_t)(e * 256 + wid * 64) * 8;   // wave-uniform
    __builtin_amdgcn_global_load_lds(
        (const __attribute__((address_space(1))) void*)src,
        (__attribute__((address_space(3))) void*)dst, 16, 0, 0);
  }
}

// ---------------- K1: projections, 128x128 tile, BK=64, fused x-cast ---------
// 1536 blocks: xcd = bid&7 owns 16 contiguous m-slabs x 4 n x 3 z.
// A staged from fp32 x: reg-load -> RNE bf16 -> swizzled ds_write (same
// layout as stage128x64: lds[row][s] = src col s^(row&7)).
__global__ __launch_bounds__(256) void k_proj(
    const float* __restrict__ xf, const unsigned short* __restrict__ Wb,
    unsigned short* __restrict__ PQ, unsigned short* __restrict__ PK,
    unsigned short* __restrict__ PKt, unsigned short* __restrict__ Vt,
    float* __restrict__ zsum)
{
  __shared__ unsigned short Al[2 * 8192], Bl[2 * 8192];   // 64 KB
  __shared__ float zbuf[2][128];
  const int bid = blockIdx.x;
  const int xcd = bid & 7, idx = bid >> 3;            // idx in 0..191
  const int n = idx & 3, z = (idx >> 2) % 3, mloc = idx / 12;
  const int n0 = n * 128, m0 = (xcd * 16 + mloc) * 128;
  const int t = threadIdx.x, wid = t >> 6, lane = t & 63;
  const int wm = wid >> 1, wn = wid & 1;
  const int fr = lane & 15, kb = lane >> 4;
  f32x4 acc[4][4];
  const f32x4 zero = {0.f, 0.f, 0.f, 0.f};
#pragma unroll
  for (int m = 0; m < 4; ++m)
#pragma unroll
    for (int nn = 0; nn < 4; ++nn) acc[m][nn] = zero;

  // A reg-stage addressing: thread -> (row = t>>3, src col slot cs = t&7)
  const int arow = t >> 3;                  // 0..31 (e adds 32)
  const int acs  = t & 7;
  const float* xp = xf + (size_t)(m0 + arow) * Cn + acs * 8;
  const int awoff = arow * 64 + (((acs ^ (arow & 7)) & 7) << 3);  // ushort idx
  const unsigned short* Bg = Wb + (size_t)z * Cn * Cn + (size_t)n0 * Cn;

  float4 a0[4], a1[4];
#pragma unroll
  for (int e = 0; e < 4; ++e) {             // A(0) -> regs
    a0[e] = *(const float4*)(xp + (size_t)e * 32 * Cn);
    a1[e] = *(const float4*)(xp + (size_t)e * 32 * Cn + 4);
  }
  stage128x64(Bg, Cn, Bl, wid, lane);       // B(0) -> LDS

  int cur = 0;
  for (int kt = 0; kt < 8; ++kt) {          // BK=64: 8 k-steps over K=512
    const int nxt = cur ^ 1;
    unsigned short* bufA = Al + cur * 8192;
#pragma unroll
    for (int e = 0; e < 4; ++e)             // convert + swizzled ds_write A(kt)
      *(uint4*)&bufA[awoff + e * 2048] = pack8(a0[e], a1[e]);
    if (kt + 1 < 8) {
#pragma unroll
      for (int e = 0; e < 4; ++e) {         // A(kt+1) -> regs
        a0[e] = *(const float4*)(xp + (size_t)e * 32 * Cn + (kt + 1) * 64);
        a1[e] = *(const float4*)(xp + (size_t)e * 32 * Cn + (kt + 1) * 64 + 4);
      }
      stage128x64(Bg + (kt + 1) * 64, Cn, Bl + nxt * 8192, wid, lane);
      asm volatile("s_waitcnt vmcnt(12)" ::: "memory");  // drain B(kt)
    } else {
      asm volatile("s_waitcnt vmcnt(0)" ::: "memory");
    }
    asm volatile("s_waitcnt lgkmcnt(0)" ::: "memory");   // A ds_writes visible
    __builtin_amdgcn_s_barrier();
    asm volatile("" ::: "memory");
    const unsigned short* Ac = Al + cur * 8192;
    const unsigned short* Bc = Bl + cur * 8192;
#pragma unroll
    for (int kk = 0; kk < 2; ++kk) {        // two K=32 sub-tiles
      bf16x8 af[4], bf[4];
#pragma unroll
      for (int m = 0; m < 4; ++m) {
        const int r = wm * 64 + m * 16 + fr;
        af[m] = *(const bf16x8*)&Ac[r * 64 + (((kk * 4 + kb) ^ (r & 7)) << 3)];
      }
#pragma unroll
      for (int nn = 0; nn < 4; ++nn) {
        const int r = wn * 64 + nn * 16 + fr;
        bf[nn] = *(const bf16x8*)&Bc[r * 64 + (((kk * 4 + kb) ^ (r & 7)) << 3)];
      }
      __builtin_amdgcn_s_setprio(1);
#pragma unroll
      for (int m = 0; m < 4; ++m)
#pragma unroll
        for (int nn = 0; nn < 4; ++nn)
          acc[m][nn] = __builtin_amdgcn_mfma_f32_16x16x32_bf16(af[m], bf[nn], acc[m][nn], 0, 0, 0);
      __builtin_amdgcn_s_setprio(0);
    }
    __builtin_amdgcn_s_barrier();           // all waves done reading cur
    asm volatile("" ::: "memory");
    cur = nxt;
  }

  float ps[4] = {0.f, 0.f, 0.f, 0.f};
#pragma unroll
  for (int m = 0; m < 4; ++m)
#pragma unroll
    for (int nn = 0; nn < 4; ++nn) {
      const int row0 = m0 + wm * 64 + m * 16 + ((lane >> 4) << 2);
      const int col  = n0 + wn * 64 + nn * 16 + fr;
      f32x4 v = acc[m][nn];
      if (z == 0) {
#pragma unroll
        for (int j = 0; j < 4; ++j)
          PQ[(size_t)(row0 + j) * Cn + col] = f2bf(phi_f(v[j]));
      } else if (z == 1) {
        ushort4 p;
#pragma unroll
        for (int j = 0; j < 4; ++j) {
          unsigned short u = f2bf(phi_f(v[j]));
          PK[(size_t)(row0 + j) * Cn + col] = u;
          (&p.x)[j] = u;
          ps[nn] += bf2f(u);
        }
        const int b = row0 >> 11, tq = row0 & (Sn - 1);
        *(ushort4*)&PKt[((size_t)b * Cn + col) * Sn + tq] = p;
      } else {
        ushort4 p;
#pragma unroll
        for (int j = 0; j < 4; ++j) (&p.x)[j] = f2bf(v[j]);
        const int b = row0 >> 11, tq = row0 & (Sn - 1);
        *(ushort4*)&Vt[((size_t)b * Cn + col) * Sn + tq] = p;
      }
    }

  if (z == 1) {   // block covers one (b, chunk) x cols n0..n0+127 completely
#pragma unroll
    for (int nn = 0; nn < 4; ++nn) {
      float v = ps[nn];
      v += __shfl_xor(v, 16); v += __shfl_xor(v, 32);   // reduce over kb
      if (lane < 16) zbuf[wm][wn * 64 + nn * 16 + lane] = v;
    }
    __syncthreads();
    if (t < 128) {
      const int b = m0 >> 11, ch = (m0 >> 7) & 15;
      zsum[((size_t)b * NCn + ch) * Cn + n0 + t] = zbuf[0][t] + zbuf[1][t];
    }
  }
}

// ---- gram staging: A 64x32 (1 load/thread), B 128x32 (2 loads/thread) -------
__device__ __forceinline__ void stageA64(const unsigned short* __restrict__ g,
                                         unsigned short* lds, int wid, int lane) {
  const int row = wid * 16 + (lane >> 2);
  const int ks  = (lane & 3) ^ ((row >> 1) & 3);
  __builtin_amdgcn_global_load_lds(
      (const __attribute__((address_space(1))) void*)(g + (size_t)row * Cn + ks * 8),
      (__attribute__((address_space(3))) void*)(lds + wid * 512), 16, 0, 0);
}
__device__ __forceinline__ void stageB128(const unsigned short* __restrict__ g,
                                          unsigned short* lds, int wid, int lane) {
#pragma unroll
  for (int e = 0; e < 2; ++e) {
    const int row = e * 64 + wid * 16 + (lane >> 2);
    const int ks  = (lane & 3) ^ ((row >> 1) & 3);
    __builtin_amdgcn_global_load_lds(
        (const __attribute__((address_space(1))) void*)(g + (size_t)row * Cn + ks * 8),
        (__attribute__((address_space(3))) void*)(lds + e * 2048 + wid * 512),
        16, 0, 0);
  }
}

// ---- stage a 64x128 bf16 tile global->LDS, swizzle slot ^= row&7 ------------
__device__ __forceinline__ void stage64x128(const unsigned short* __restrict__ g,
                                            int ld, unsigned short* lds,
                                            int wid, int lane) {
#pragma unroll
  for (int i = 0; i < 4; ++i) {
    const int row = wid * 16 + i * 4 + (lane >> 4);
    const int s   = (lane & 15) ^ (row & 7);
    const unsigned short* src = g + (size_t)row * ld + s * 8;
    unsigned short* dst = lds + (size_t)(wid * 16 + i * 4) * 128;   // wave-uniform
    __builtin_amdgcn_global_load_lds(
        (const __attribute__((address_space(1))) void*)src,
        (__attribute__((address_space(3))) void*)dst, 16, 0, 0);
  }
}

// ---------------- K2: merged gram (blocks 512..767) + kvp (blocks 0..511) ----
__global__ __launch_bounds__(256) void k_gk(
    const unsigned short* __restrict__ PQ, const unsigned short* __restrict__ PK,
    const float* __restrict__ zsum,
    unsigned short* __restrict__ Abuf, float* __restrict__ scale,
    const unsigned short* __restrict__ PKt, const unsigned short* __restrict__ Vt,
    unsigned short* __restrict__ Mpre)
{
  __shared__ unsigned short smem[32768];   // 64 KB union
  const int t = threadIdx.x, wid = t >> 6, lane = t & 63;
  const int fr = lane & 15, kb = lane >> 4;
  const f32x4 zero = {0.f, 0.f, 0.f, 0.f};

  if (blockIdx.x < 512) {
    // ---------------- kvp: KV + exclusive prefix (BK=128) -------------------
    unsigned short* Al = smem;                  // 2 x 8192
    unsigned short* Bl = smem + 16384;          // 2 x 8192
    const int bid = blockIdx.x;
    const int b = bid & 7, idx = bid >> 3;
    const int d0 = (idx & 7) * 64, c0 = (idx >> 3) * 64;
    const int wm = wid >> 1, wn = wid & 1;
    f32x4 acc[2][2];
#pragma unroll
    for (int m = 0; m < 2; ++m)
#pragma unroll
      for (int n = 0; n < 2; ++n) acc[m][n] = zero;
    const unsigned short* Ag = PKt + ((size_t)b * Cn + c0) * Sn;
    const unsigned short* Bg = Vt  + ((size_t)b * Cn + d0) * Sn;
    stage64x128(Ag, Sn, Al, wid, lane);
    stage64x128(Bg, Sn, Bl, wid, lane);
    int cur = 0;
    for (int ch = 0; ch < NCn; ++ch) {
      const int nxt = cur ^ 1;
      if (ch + 1 < NCn) {
        stage64x128(Ag + (ch + 1) * Tn, Sn, Al + nxt * 8192, wid, lane);
        stage64x128(Bg + (ch + 1) * Tn, Sn, Bl + nxt * 8192, wid, lane);
        asm volatile("s_waitcnt vmcnt(8)" ::: "memory");
      } else {
        asm volatile("s_waitcnt vmcnt(0)" ::: "memory");
      }
      __builtin_amdgcn_s_barrier();
      asm volatile("" ::: "memory");
      if (ch > 0) {
#pragma unroll
        for (int m = 0; m < 2; ++m)
#pragma unroll
          for (int n = 0; n < 2; ++n) {
            const int c_row = c0 + wm * 32 + m * 16 + (kb << 2);
            const int d     = d0 + wn * 32 + n * 16 + fr;
            ushort4 p;
#pragma unroll
            for (int j = 0; j < 4; ++j) (&p.x)[j] = f2bf(acc[m][n][j]);
            *(ushort4*)&Mpre[((size_t)(b * NCn + ch) * Cn + d) * Cn + c_row] = p;
          }
      }
      const unsigned short* Ac = Al + cur * 8192;
      const unsigned short* Bc = Bl + cur * 8192;
      __builtin_amdgcn_s_setprio(1);
#pragma unroll
      for (int kt = 0; kt < 4; ++kt) {
        bf16x8 af[2], bf[2];
#pragma unroll
        for (int m = 0; m < 2; ++m) {
          const int r = wm * 32 + m * 16 + fr;
          af[m] = *(const bf16x8*)&Ac[r * 128 + (((kt * 4 + kb) ^ (r & 7)) << 3)];
        }
#pragma unroll
        for (int n = 0; n < 2; ++n) {
          const int r = wn * 32 + n * 16 + fr;
          bf[n] = *(const bf16x8*)&Bc[r * 128 + (((kt * 4 + kb) ^ (r & 7)) << 3)];
        }
#pragma unroll
        for (int m = 0; m < 2; ++m)
#pragma unroll
          for (int n = 0; n < 2; ++n)
            acc[m][n] = __builtin_amdgcn_mfma_f32_16x16x32_bf16(af[m], bf[n], acc[m][n], 0, 0, 0);
      }
      __builtin_amdgcn_s_setprio(0);
      __builtin_amdgcn_s_barrier();
      asm volatile("" ::: "memory");
      cur = nxt;
    }
  } else {
    // ---------------- gram: A = tril(PQ_c PK_c^T), scale fused --------------
    unsigned short* Asl = smem;                 // 3 x 2048
    unsigned short* Bsl = smem + 6144;          // 3 x 4096
    float* rsmem = (float*)(smem + 18432);      // [4][64]
    float* zpl   = rsmem + 256;                 // [512]
    const int g = blockIdx.x - 512;
    const int i0 = (g & 1) * 64, ch = (g >> 1) & 15, b = g >> 5;
    const unsigned short* Aq = PQ + ((size_t)(b * Sn + ch * Tn + i0)) * Cn;
    const unsigned short* Bk = PK + ((size_t)(b * Sn + ch * Tn)) * Cn;
    f32x4 acc[4][2];
#pragma unroll
    for (int m = 0; m < 4; ++m)
#pragma unroll
      for (int n = 0; n < 2; ++n) acc[m][n] = zero;

    stageA64(Aq, Asl, wid, lane);
    stageB128(Bk, Bsl, wid, lane);
    stageA64(Aq + 32, Asl + 2048, wid, lane);
    stageB128(Bk + 32, Bsl + 4096, wid, lane);
    int cur = 0;
    for (int kt = 0; kt < 16; ++kt) {
      if (kt + 2 < 16) {
        const int nx2 = (cur + 2 >= 3) ? cur - 1 : cur + 2;
        stageA64(Aq + (kt + 2) * 32, Asl + nx2 * 2048, wid, lane);
        stageB128(Bk + (kt + 2) * 32, Bsl + nx2 * 4096, wid, lane);
        asm volatile("s_waitcnt vmcnt(6)" ::: "memory");
      } else if (kt + 1 < 16) {
        asm volatile("s_waitcnt vmcnt(3)" ::: "memory");
      } else {
        asm volatile("s_waitcnt vmcnt(0)" ::: "memory");
      }
      __builtin_amdgcn_s_barrier();
      asm volatile("" ::: "memory");
      const unsigned short* Ac = Asl + cur * 2048;
      const unsigned short* Bc = Bsl + cur * 4096;
      bf16x8 af[4], bf[2];
#pragma unroll
      for (int m = 0; m < 4; ++m) {
        const int r = m * 16 + fr;
        af[m] = *(const bf16x8*)&Ac[r * 32 + ((kb ^ ((r >> 1) & 3)) << 3)];
      }
#pragma unroll
      for (int n = 0; n < 2; ++n) {
        const int c = wid * 32 + n * 16 + fr;
        bf[n] = *(const bf16x8*)&Bc[c * 32 + ((kb ^ ((c >> 1) & 3)) << 3)];
      }
      __builtin_amdgcn_s_setprio(1);
#pragma unroll
      for (int m = 0; m < 4; ++m)
#pragma unroll
        for (int n = 0; n < 2; ++n)
          acc[m][n] = __builtin_amdgcn_mfma_f32_16x16x32_bf16(af[m], bf[n], acc[m][n], 0, 0, 0);
      __builtin_amdgcn_s_setprio(0);
      __builtin_amdgcn_s_barrier();
      asm volatile("" ::: "memory");
      cur = (cur + 1 >= 3) ? 0 : cur + 1;
    }

    float rsum[4][4];
#pragma unroll
    for (int m = 0; m < 4; ++m)
#pragma unroll
      for (int j = 0; j < 4; ++j) rsum[m][j] = 0.f;
#pragma unroll
    for (int m = 0; m < 4; ++m)
#pragma unroll
      for (int n = 0; n < 2; ++n) {
        f32x4 v = acc[m][n];
#pragma unroll
        for (int j = 0; j < 4; ++j) {
          const int row_g = i0 + m * 16 + kb * 4 + j;     // chunk-local row
          const int col   = wid * 32 + n * 16 + fr;
          unsigned short u = (col <= row_g) ? f2bf(v[j]) : 0;
          Abuf[((size_t)(b * NCn + ch) * Tn + row_g) * Tn + col] = u;
          rsum[m][j] += bf2f(u);
        }
      }
#pragma unroll
    for (int m = 0; m < 4; ++m)
#pragma unroll
      for (int j = 0; j < 4; ++j) {
        float r = rsum[m][j];
        r += __shfl_xor(r, 1); r += __shfl_xor(r, 2);
        r += __shfl_xor(r, 4); r += __shfl_xor(r, 8);
        if (fr == 0) rsmem[wid * 64 + m * 16 + kb * 4 + j] = r;
      }
    // exclusive chunk-prefix of zsum -> zpl
#pragma unroll
    for (int e = 0; e < 2; ++e) {
      const int c = t + e * 256;
      float s = 0.f;
      for (int ch2 = 0; ch2 < ch; ++ch2)
        s += zsum[((size_t)b * NCn + ch2) * Cn + c];
      zpl[c] = s;
    }
    __syncthreads();
    // per-row dot(PQ_row, zpl): 4 threads per row, 128 cols each
    const int row = t >> 2, q4 = (t & 3) * 128;
    const unsigned short* pq = Aq + (size_t)row * Cn + q4;
    float dacc = 0.f;
    for (int i = 0; i < 128; i += 8) {
      uint4 q = *(const uint4*)(pq + i);
      dacc += bf2f((unsigned short)(q.x & 0xffff)) * zpl[q4 + i + 0]
            + bf2f((unsigned short)(q.x >> 16))    * zpl[q4 + i + 1]
            + bf2f((unsigned short)(q.y & 0xffff)) * zpl[q4 + i + 2]
            + bf2f((unsigned short)(q.y >> 16))    * zpl[q4 + i + 3]
            + bf2f((unsigned short)(q.z & 0xffff)) * zpl[q4 + i + 4]
            + bf2f((unsigned short)(q.z >> 16))    * zpl[q4 + i + 5]
            + bf2f((unsigned short)(q.w & 0xffff)) * zpl[q4 + i + 6]
            + bf2f((unsigned short)(q.w >> 16))    * zpl[q4 + i + 7];
    }
    dacc += __shfl_xor(dacc, 1);
    dacc += __shfl_xor(dacc, 2);
    if ((t & 3) == 0)
      scale[(size_t)b * Sn + ch * Tn + i0 + row] =
          rsmem[0 * 64 + row] + rsmem[1 * 64 + row] +
          rsmem[2 * 64 + row] + rsmem[3 * 64 + row] + dacc + 1e-5f;
  }
}

// ---- stage a 128x32 bf16 tile global->LDS (256 thr), kslot ^= (row>>1)&3 ----
__device__ __forceinline__ void stage128x32(const unsigned short* __restrict__ g,
                                            int ld, unsigned short* lds,
                                            int wid, int lane) {
#pragma unroll
  for (int cc = 0; cc < 2; ++cc) {
    const int row = cc * 64 + wid * 16 + (lane >> 2);
    const int ks  = (lane & 3) ^ ((row >> 1) & 3);
    const unsigned short* src = g + (size_t)row * ld + ks * 8;
    unsigned short* dst = lds + (size_t)(cc * 256 + wid * 64) * 8;  // wave-uniform
    __builtin_amdgcn_global_load_lds(
        (const __attribute__((address_space(1))) void*)src,
        (__attribute__((address_space(3))) void*)dst, 16, 0, 0);
  }
}

// ---------------- K3: out = (A@V_c + PQ_c@Mpre_c) / scale --------------------
// Single fused 20-step pipelined K-loop (intra kt<4, inter kt>=4).
__global__ __launch_bounds__(256) void k_avinter(
    const unsigned short* __restrict__ Abuf, const unsigned short* __restrict__ Vt,
    const unsigned short* __restrict__ PQ, const unsigned short* __restrict__ Mpre,
    const float* __restrict__ scale, float* __restrict__ out)
{
  __shared__ unsigned short Al[3 * 128 * 32], Bl[3 * 128 * 32];
  const int bid = blockIdx.x;
  const int logical = (bid & 7) * 64 + (bid >> 3);
  const int d0 = (logical & 3) * 128;
  const int ch = (logical >> 2) & 15;
  const int b  = logical >> 6;
  const int t0 = ch * Tn;
  const int t = threadIdx.x, wid = t >> 6, lane = t & 63;
  const int wm = wid >> 1, wn = wid & 1;
  const int fr = lane & 15, kb = lane >> 4;
  f32x4 acc[4][4];
  const f32x4 zero = {0.f, 0.f, 0.f, 0.f};
#pragma unroll
  for (int m = 0; m < 4; ++m)
#pragma unroll
    for (int n = 0; n < 4; ++n) acc[m][n] = zero;

  const unsigned short* Aintra = Abuf + (size_t)(b * NCn + ch) * Tn * Tn;
  const unsigned short* Bintra = Vt + ((size_t)b * Cn + d0) * Sn + t0;
  const unsigned short* Ainter = PQ + ((size_t)b * Sn + t0) * Cn;
  const unsigned short* Binter = Mpre + ((size_t)(b * NCn + ch) * Cn + d0) * Cn;
  auto srcA = [&](int kt) { return (kt < 4) ? Aintra + kt * 32 : Ainter + (kt - 4) * 32; };
  auto srcB = [&](int kt) { return (kt < 4) ? Bintra + kt * 32 : Binter + (kt - 4) * 32; };
  auto ldA  = [&](int kt) { return (kt < 4) ? Tn : Cn; };
  auto ldB  = [&](int kt) { return (kt < 4) ? Sn : Cn; };
  const int nkt = (ch > 0) ? 20 : 4;

  stage128x32(srcA(0), ldA(0), Al, wid, lane);
  stage128x32(srcB(0), ldB(0), Bl, wid, lane);
  stage128x32(srcA(1), ldA(1), Al + 4096, wid, lane);
  stage128x32(srcB(1), ldB(1), Bl + 4096, wid, lane);
  int cur = 0;
  for (int kt = 0; kt < nkt; ++kt) {
    if (kt + 2 < nkt) {
      const int nx2 = (cur + 2 >= 3) ? cur - 1 : cur + 2;
      stage128x32(srcA(kt + 2), ldA(kt + 2), Al + nx2 * 4096, wid, lane);
      stage128x32(srcB(kt + 2), ldB(kt + 2), Bl + nx2 * 4096, wid, lane);
      asm volatile("s_waitcnt vmcnt(8)" ::: "memory");
    } else if (kt + 1 < nkt) {
      asm volatile("s_waitcnt vmcnt(4)" ::: "memory");
    } else {
      asm volatile("s_waitcnt vmcnt(0)" ::: "memory");
    }
    __builtin_amdgcn_s_barrier();
    asm volatile("" ::: "memory");
    const unsigned short* Ac = Al + cur * 4096;
    const unsigned short* Bc = Bl + cur * 4096;
    bf16x8 af[4], bf[4];
#pragma unroll
    for (int m = 0; m < 4; ++m) {
      const int r = wm * 64 + m * 16 + fr;
      af[m] = *(const bf16x8*)&Ac[r * 32 + ((kb ^ ((r >> 1) & 3)) << 3)];
    }
#pragma unroll
    for (int n = 0; n < 4; ++n) {
      const int r = wn * 64 + n * 16 + fr;
      bf[n] = *(const bf16x8*)&Bc[r * 32 + ((kb ^ ((r >> 1) & 3)) << 3)];
    }
    __builtin_amdgcn_s_setprio(1);
#pragma unroll
    for (int m = 0; m < 4; ++m)
#pragma unroll
      for (int n = 0; n < 4; ++n)
        acc[m][n] = __builtin_amdgcn_mfma_f32_16x16x32_bf16(af[m], bf[n], acc[m][n], 0, 0, 0);
    __builtin_amdgcn_s_setprio(0);
    __builtin_amdgcn_s_barrier();
    asm volatile("" ::: "memory");
    cur = (cur + 1 >= 3) ? 0 : cur + 1;
  }

#pragma unroll
  for (int m = 0; m < 4; ++m)
#pragma unroll
    for (int n = 0; n < 4; ++n) {
      const int row0 = t0 + wm * 64 + m * 16 + ((lane >> 4) << 2);
      const int col  = d0 + wn * 64 + n * 16 + (lane & 15);
      f32x4 v = acc[m][n];
#pragma unroll
      for (int j = 0; j < 4; ++j) {
        const size_t sidx = (size_t)b * Sn + row0 + j;
        out[sidx * Cn + col] = v[j] / scale[sidx];
      }
    }
}

// ---------------- launch -----------------------------------------------------
extern "C" void kernel_launch(void* const* d_in, const int* in_sizes, int n_in,
                              void* d_out, int out_size, void* d_ws, size_t ws_size,
                              hipStream_t stream)
{
  const float* x  = (const float*)d_in[0];
  const float* Wq = (const float*)d_in[1];
  const float* Wk = (const float*)d_in[2];
  const float* Wv = (const float*)d_in[3];
  float* out = (float*)d_out;

  unsigned short* Wb   = (unsigned short*)d_ws;                // 0.79M
  unsigned short* PQ   = Wb   + (size_t)3 * Cn * Cn;
  unsigned short* PK   = PQ   + (size_t)Bn * Sn * Cn;
  unsigned short* PKt  = PK   + (size_t)Bn * Sn * Cn;
  unsigned short* Vt   = PKt  + (size_t)Bn * Sn * Cn;
  unsigned short* Abuf = Vt   + (size_t)Bn * Sn * Cn;          // 2.10M
  unsigned short* Mpre = Abuf + (size_t)Bn * NCn * Tn * Tn;    // 33.55M
  float* scale = (float*)(Mpre + (size_t)Bn * NCn * Cn * Cn);  // 16K
  float* zsum  = scale + (size_t)Bn * Sn;                      // 64K
  (void)ws_size; (void)in_sizes; (void)n_in; (void)out_size;

  hipLaunchKernelGGL(k_castw, dim3(384), dim3(256), 0, stream, Wq, Wk, Wv, Wb);
  hipLaunchKernelGGL(k_proj, dim3(1536), dim3(256), 0, stream, x, Wb, PQ, PK, PKt, Vt, zsum);
  hipLaunchKernelGGL(k_gk, dim3(768), dim3(256), 0, stream,
                     PQ, PK, zsum, Abuf, scale, PKt, Vt, Mpre);
  hipLaunchKernelGGL(k_avinter, dim3(512), dim3(256), 0, stream, Abuf, Vt, PQ, Mpre, scale, out);
}

// Round 16
// 118.101 us; speedup vs baseline: 1.0895x; 1.0895x over previous
//
#include <hip/hip_runtime.h>

// LinearAttentionCell: chunked linear attention, bf16 MFMA.
// R16 = exact revert to R14 (best, 118.4us): BK=64 proj (8 k-steps, 2-buf
// counted vmcnt), merged cast, merged gram+kvp launch, fused avinter.
// R15's fused x-cast regressed (VALU-bound proj) and is reverted.

constexpr int Bn  = 8;
constexpr int Sn  = 2048;
constexpr int Cn  = 512;
constexpr int Tn  = 128;
constexpr int NCn = 16;
constexpr float DKf = 0.04419417382415922f;     // 1/sqrt(512)

typedef __attribute__((ext_vector_type(8))) short bf16x8;
typedef __attribute__((ext_vector_type(4))) float f32x4;

__device__ __forceinline__ unsigned short f2bf(float f) {   // RNE
  unsigned u = __float_as_uint(f);
  u = (u + 0x7fffu + ((u >> 16) & 1u)) >> 16;
  return (unsigned short)u;
}
__device__ __forceinline__ float bf2f(unsigned short h) {
  return __uint_as_float(((unsigned)h) << 16);
}
__device__ __forceinline__ float phi_f(float u) {
  float s = u * DKf;
  return s > 0.0f ? s + 1.0f : __expf(s);       // elu(s)+1
}

// ---------------- merged cast: x -> xb, {Wq,Wk,Wv} -> Wb ---------------------
__global__ __launch_bounds__(256) void k_cast(
    const float* __restrict__ x, const float* __restrict__ Wq,
    const float* __restrict__ Wk, const float* __restrict__ Wv,
    unsigned short* __restrict__ xb, unsigned short* __restrict__ Wb)
{
  const int bid = blockIdx.x;
  const float* src;
  unsigned short* dst;
  size_t i8;
  if (bid < 4096) {
    i8 = ((size_t)bid * 256 + threadIdx.x) * 8;
    src = x; dst = xb;
  } else {
    const size_t f = ((size_t)(bid - 4096) * 256 + threadIdx.x) * 8;
    const int z = (int)(f >> 18);                    // / (512*512)
    src = (z == 0) ? Wq : (z == 1 ? Wk : Wv);
    dst = Wb + ((size_t)z << 18);
    i8 = f & ((1u << 18) - 1);
  }
  float4 a = *(const float4*)&src[i8];
  float4 b = *(const float4*)&src[i8 + 4];
  uint4 o;
  o.x = (unsigned)f2bf(a.x) | ((unsigned)f2bf(a.y) << 16);
  o.y = (unsigned)f2bf(a.z) | ((unsigned)f2bf(a.w) << 16);
  o.z = (unsigned)f2bf(b.x) | ((unsigned)f2bf(b.y) << 16);
  o.w = (unsigned)f2bf(b.z) | ((unsigned)f2bf(b.w) << 16);
  *(uint4*)&dst[i8] = o;
}

// ---- stage a 128x64 bf16 tile global->LDS (256 thr, 4 issues/thread) --------
// 8 slots of 16B per row; swizzle slot ^= row&7 (8-row period, conflict-free).
__device__ __forceinline__ void stage128x64(const unsigned short* __restrict__ g,
                                            int ld, unsigned short* lds,
                                            int wid, int lane) {
#pragma unroll
  for (int e = 0; e < 4; ++e) {
    const int row = e * 32 + wid * 8 + (lane >> 3);
    const int ks  = (lane & 7) ^ (row & 7);
    const unsigned short* src = g + (size_t)row * ld + ks * 8;
    unsigned short* dst = lds + (size_t)(e * 256 + wid * 64) * 8;   // wave-uniform
    __builtin_amdgcn_global_load_lds(
        (const __attribute__((address_space(1))) void*)src,
        (__attribute__((address_space(3))) void*)dst, 16, 0, 0);
  }
}

// ---------------- K1: projections, 128x128 tile, BK=64, 8 k-steps ------------
// 1536 blocks: xcd = bid&7 owns 16 contiguous m-slabs x 4 n x 3 z.
// 2-buffer depth-1 pipeline: stage(kt+1) -> vmcnt(8) -> bar -> 32 MFMA -> bar.
__global__ __launch_bounds__(256) void k_proj(
    const unsigned short* __restrict__ xb, const unsigned short* __restrict__ Wb,
    unsigned short* __restrict__ PQ, unsigned short* __restrict__ PK,
    unsigned short* __restrict__ PKt, unsigned short* __restrict__ Vt,
    float* __restrict__ zsum)
{
  __shared__ unsigned short Al[2 * 8192], Bl[2 * 8192];   // 64 KB
  __shared__ float zbuf[2][128];
  const int bid = blockIdx.x;
  const int xcd = bid & 7, idx = bid >> 3;            // idx in 0..191
  const int n = idx & 3, z = (idx >> 2) % 3, mloc = idx / 12;
  const int n0 = n * 128, m0 = (xcd * 16 + mloc) * 128;
  const int t = threadIdx.x, wid = t >> 6, lane = t & 63;
  const int wm = wid >> 1, wn = wid & 1;
  const int fr = lane & 15, kb = lane >> 4;
  f32x4 acc[4][4];
  const f32x4 zero = {0.f, 0.f, 0.f, 0.f};
#pragma unroll
  for (int m = 0; m < 4; ++m)
#pragma unroll
    for (int nn = 0; nn < 4; ++nn) acc[m][nn] = zero;

  const unsigned short* Ag = xb + (size_t)m0 * Cn;
  const unsigned short* Bg = Wb + (size_t)z * Cn * Cn + (size_t)n0 * Cn;

  stage128x64(Ag, Cn, Al, wid, lane);
  stage128x64(Bg, Cn, Bl, wid, lane);
  int cur = 0;
  for (int kt = 0; kt < 8; ++kt) {            // BK=64: 8 k-steps over K=512
    const int nxt = cur ^ 1;
    if (kt + 1 < 8) {
      stage128x64(Ag + (kt + 1) * 64, Cn, Al + nxt * 8192, wid, lane);
      stage128x64(Bg + (kt + 1) * 64, Cn, Bl + nxt * 8192, wid, lane);
      asm volatile("s_waitcnt vmcnt(8)" ::: "memory");   // tile kt landed
    } else {
      asm volatile("s_waitcnt vmcnt(0)" ::: "memory");
    }
    __builtin_amdgcn_s_barrier();
    asm volatile("" ::: "memory");
    const unsigned short* Ac = Al + cur * 8192;
    const unsigned short* Bc = Bl + cur * 8192;
#pragma unroll
    for (int kk = 0; kk < 2; ++kk) {          // two K=32 sub-tiles
      bf16x8 af[4], bf[4];
#pragma unroll
      for (int m = 0; m < 4; ++m) {
        const int r = wm * 64 + m * 16 + fr;
        af[m] = *(const bf16x8*)&Ac[r * 64 + (((kk * 4 + kb) ^ (r & 7)) << 3)];
      }
#pragma unroll
      for (int nn = 0; nn < 4; ++nn) {
        const int r = wn * 64 + nn * 16 + fr;
        bf[nn] = *(const bf16x8*)&Bc[r * 64 + (((kk * 4 + kb) ^ (r & 7)) << 3)];
      }
      __builtin_amdgcn_s_setprio(1);
#pragma unroll
      for (int m = 0; m < 4; ++m)
#pragma unroll
        for (int nn = 0; nn < 4; ++nn)
          acc[m][nn] = __builtin_amdgcn_mfma_f32_16x16x32_bf16(af[m], bf[nn], acc[m][nn], 0, 0, 0);
      __builtin_amdgcn_s_setprio(0);
    }
    __builtin_amdgcn_s_barrier();             // all waves done reading cur
    asm volatile("" ::: "memory");
    cur = nxt;
  }

  float ps[4] = {0.f, 0.f, 0.f, 0.f};
#pragma unroll
  for (int m = 0; m < 4; ++m)
#pragma unroll
    for (int nn = 0; nn < 4; ++nn) {
      const int row0 = m0 + wm * 64 + m * 16 + ((lane >> 4) << 2);
      const int col  = n0 + wn * 64 + nn * 16 + fr;
      f32x4 v = acc[m][nn];
      if (z == 0) {
#pragma unroll
        for (int j = 0; j < 4; ++j)
          PQ[(size_t)(row0 + j) * Cn + col] = f2bf(phi_f(v[j]));
      } else if (z == 1) {
        ushort4 p;
#pragma unroll
        for (int j = 0; j < 4; ++j) {
          unsigned short u = f2bf(phi_f(v[j]));
          PK[(size_t)(row0 + j) * Cn + col] = u;
          (&p.x)[j] = u;
          ps[nn] += bf2f(u);
        }
        const int b = row0 >> 11, tq = row0 & (Sn - 1);
        *(ushort4*)&PKt[((size_t)b * Cn + col) * Sn + tq] = p;
      } else {
        ushort4 p;
#pragma unroll
        for (int j = 0; j < 4; ++j) (&p.x)[j] = f2bf(v[j]);
        const int b = row0 >> 11, tq = row0 & (Sn - 1);
        *(ushort4*)&Vt[((size_t)b * Cn + col) * Sn + tq] = p;
      }
    }

  if (z == 1) {   // block covers one (b, chunk) x cols n0..n0+127 completely
#pragma unroll
    for (int nn = 0; nn < 4; ++nn) {
      float v = ps[nn];
      v += __shfl_xor(v, 16); v += __shfl_xor(v, 32);   // reduce over kb
      if (lane < 16) zbuf[wm][wn * 64 + nn * 16 + lane] = v;
    }
    __syncthreads();
    if (t < 128) {
      const int b = m0 >> 11, ch = (m0 >> 7) & 15;
      zsum[((size_t)b * NCn + ch) * Cn + n0 + t] = zbuf[0][t] + zbuf[1][t];
    }
  }
}

// ---- gram staging: A 64x32 (1 load/thread), B 128x32 (2 loads/thread) -------
__device__ __forceinline__ void stageA64(const unsigned short* __restrict__ g,
                                         unsigned short* lds, int wid, int lane) {
  const int row = wid * 16 + (lane >> 2);
  const int ks  = (lane & 3) ^ ((row >> 1) & 3);
  __builtin_amdgcn_global_load_lds(
      (const __attribute__((address_space(1))) void*)(g + (size_t)row * Cn + ks * 8),
      (__attribute__((address_space(3))) void*)(lds + wid * 512), 16, 0, 0);
}
__device__ __forceinline__ void stageB128(const unsigned short* __restrict__ g,
                                          unsigned short* lds, int wid, int lane) {
#pragma unroll
  for (int e = 0; e < 2; ++e) {
    const int row = e * 64 + wid * 16 + (lane >> 2);
    const int ks  = (lane & 3) ^ ((row >> 1) & 3);
    __builtin_amdgcn_global_load_lds(
        (const __attribute__((address_space(1))) void*)(g + (size_t)row * Cn + ks * 8),
        (__attribute__((address_space(3))) void*)(lds + e * 2048 + wid * 512),
        16, 0, 0);
  }
}

// ---- stage a 64x128 bf16 tile global->LDS, swizzle slot ^= row&7 ------------
__device__ __forceinline__ void stage64x128(const unsigned short* __restrict__ g,
                                            int ld, unsigned short* lds,
                                            int wid, int lane) {
#pragma unroll
  for (int i = 0; i < 4; ++i) {
    const int row = wid * 16 + i * 4 + (lane >> 4);
    const int s   = (lane & 15) ^ (row & 7);
    const unsigned short* src = g + (size_t)row * ld + s * 8;
    unsigned short* dst = lds + (size_t)(wid * 16 + i * 4) * 128;   // wave-uniform
    __builtin_amdgcn_global_load_lds(
        (const __attribute__((address_space(1))) void*)src,
        (__attribute__((address_space(3))) void*)dst, 16, 0, 0);
  }
}

// ---------------- K2: merged gram (blocks 512..767) + kvp (blocks 0..511) ----
__global__ __launch_bounds__(256) void k_gk(
    const unsigned short* __restrict__ PQ, const unsigned short* __restrict__ PK,
    const float* __restrict__ zsum,
    unsigned short* __restrict__ Abuf, float* __restrict__ scale,
    const unsigned short* __restrict__ PKt, const unsigned short* __restrict__ Vt,
    unsigned short* __restrict__ Mpre)
{
  __shared__ unsigned short smem[32768];   // 64 KB union
  const int t = threadIdx.x, wid = t >> 6, lane = t & 63;
  const int fr = lane & 15, kb = lane >> 4;
  const f32x4 zero = {0.f, 0.f, 0.f, 0.f};

  if (blockIdx.x < 512) {
    // ---------------- kvp: KV + exclusive prefix (BK=128) -------------------
    unsigned short* Al = smem;                  // 2 x 8192
    unsigned short* Bl = smem + 16384;          // 2 x 8192
    const int bid = blockIdx.x;
    const int b = bid & 7, idx = bid >> 3;
    const int d0 = (idx & 7) * 64, c0 = (idx >> 3) * 64;
    const int wm = wid >> 1, wn = wid & 1;
    f32x4 acc[2][2];
#pragma unroll
    for (int m = 0; m < 2; ++m)
#pragma unroll
      for (int n = 0; n < 2; ++n) acc[m][n] = zero;
    const unsigned short* Ag = PKt + ((size_t)b * Cn + c0) * Sn;
    const unsigned short* Bg = Vt  + ((size_t)b * Cn + d0) * Sn;
    stage64x128(Ag, Sn, Al, wid, lane);
    stage64x128(Bg, Sn, Bl, wid, lane);
    int cur = 0;
    for (int ch = 0; ch < NCn; ++ch) {
      const int nxt = cur ^ 1;
      if (ch + 1 < NCn) {
        stage64x128(Ag + (ch + 1) * Tn, Sn, Al + nxt * 8192, wid, lane);
        stage64x128(Bg + (ch + 1) * Tn, Sn, Bl + nxt * 8192, wid, lane);
        asm volatile("s_waitcnt vmcnt(8)" ::: "memory");
      } else {
        asm volatile("s_waitcnt vmcnt(0)" ::: "memory");
      }
      __builtin_amdgcn_s_barrier();
      asm volatile("" ::: "memory");
      if (ch > 0) {
#pragma unroll
        for (int m = 0; m < 2; ++m)
#pragma unroll
          for (int n = 0; n < 2; ++n) {
            const int c_row = c0 + wm * 32 + m * 16 + (kb << 2);
            const int d     = d0 + wn * 32 + n * 16 + fr;
            ushort4 p;
#pragma unroll
            for (int j = 0; j < 4; ++j) (&p.x)[j] = f2bf(acc[m][n][j]);
            *(ushort4*)&Mpre[((size_t)(b * NCn + ch) * Cn + d) * Cn + c_row] = p;
          }
      }
      const unsigned short* Ac = Al + cur * 8192;
      const unsigned short* Bc = Bl + cur * 8192;
      __builtin_amdgcn_s_setprio(1);
#pragma unroll
      for (int kt = 0; kt < 4; ++kt) {
        bf16x8 af[2], bf[2];
#pragma unroll
        for (int m = 0; m < 2; ++m) {
          const int r = wm * 32 + m * 16 + fr;
          af[m] = *(const bf16x8*)&Ac[r * 128 + (((kt * 4 + kb) ^ (r & 7)) << 3)];
        }
#pragma unroll
        for (int n = 0; n < 2; ++n) {
          const int r = wn * 32 + n * 16 + fr;
          bf[n] = *(const bf16x8*)&Bc[r * 128 + (((kt * 4 + kb) ^ (r & 7)) << 3)];
        }
#pragma unroll
        for (int m = 0; m < 2; ++m)
#pragma unroll
          for (int n = 0; n < 2; ++n)
            acc[m][n] = __builtin_amdgcn_mfma_f32_16x16x32_bf16(af[m], bf[n], acc[m][n], 0, 0, 0);
      }
      __builtin_amdgcn_s_setprio(0);
      __builtin_amdgcn_s_barrier();
      asm volatile("" ::: "memory");
      cur = nxt;
    }
  } else {
    // ---------------- gram: A = tril(PQ_c PK_c^T), scale fused --------------
    unsigned short* Asl = smem;                 // 3 x 2048
    unsigned short* Bsl = smem + 6144;          // 3 x 4096
    float* rsmem = (float*)(smem + 18432);      // [4][64]
    float* zpl   = rsmem + 256;                 // [512]
    const int g = blockIdx.x - 512;
    const int i0 = (g & 1) * 64, ch = (g >> 1) & 15, b = g >> 5;
    const unsigned short* Aq = PQ + ((size_t)(b * Sn + ch * Tn + i0)) * Cn;
    const unsigned short* Bk = PK + ((size_t)(b * Sn + ch * Tn)) * Cn;
    f32x4 acc[4][2];
#pragma unroll
    for (int m = 0; m < 4; ++m)
#pragma unroll
      for (int n = 0; n < 2; ++n) acc[m][n] = zero;

    stageA64(Aq, Asl, wid, lane);
    stageB128(Bk, Bsl, wid, lane);
    stageA64(Aq + 32, Asl + 2048, wid, lane);
    stageB128(Bk + 32, Bsl + 4096, wid, lane);
    int cur = 0;
    for (int kt = 0; kt < 16; ++kt) {
      if (kt + 2 < 16) {
        const int nx2 = (cur + 2 >= 3) ? cur - 1 : cur + 2;
        stageA64(Aq + (kt + 2) * 32, Asl + nx2 * 2048, wid, lane);
        stageB128(Bk + (kt + 2) * 32, Bsl + nx2 * 4096, wid, lane);
        asm volatile("s_waitcnt vmcnt(6)" ::: "memory");
      } else if (kt + 1 < 16) {
        asm volatile("s_waitcnt vmcnt(3)" ::: "memory");
      } else {
        asm volatile("s_waitcnt vmcnt(0)" ::: "memory");
      }
      __builtin_amdgcn_s_barrier();
      asm volatile("" ::: "memory");
      const unsigned short* Ac = Asl + cur * 2048;
      const unsigned short* Bc = Bsl + cur * 4096;
      bf16x8 af[4], bf[2];
#pragma unroll
      for (int m = 0; m < 4; ++m) {
        const int r = m * 16 + fr;
        af[m] = *(const bf16x8*)&Ac[r * 32 + ((kb ^ ((r >> 1) & 3)) << 3)];
      }
#pragma unroll
      for (int n = 0; n < 2; ++n) {
        const int c = wid * 32 + n * 16 + fr;
        bf[n] = *(const bf16x8*)&Bc[c * 32 + ((kb ^ ((c >> 1) & 3)) << 3)];
      }
      __builtin_amdgcn_s_setprio(1);
#pragma unroll
      for (int m = 0; m < 4; ++m)
#pragma unroll
        for (int n = 0; n < 2; ++n)
          acc[m][n] = __builtin_amdgcn_mfma_f32_16x16x32_bf16(af[m], bf[n], acc[m][n], 0, 0, 0);
      __builtin_amdgcn_s_setprio(0);
      __builtin_amdgcn_s_barrier();
      asm volatile("" ::: "memory");
      cur = (cur + 1 >= 3) ? 0 : cur + 1;
    }

    float rsum[4][4];
#pragma unroll
    for (int m = 0; m < 4; ++m)
#pragma unroll
      for (int j = 0; j < 4; ++j) rsum[m][j] = 0.f;
#pragma unroll
    for (int m = 0; m < 4; ++m)
#pragma unroll
      for (int n = 0; n < 2; ++n) {
        f32x4 v = acc[m][n];
#pragma unroll
        for (int j = 0; j < 4; ++j) {
          const int row_g = i0 + m * 16 + kb * 4 + j;     // chunk-local row
          const int col   = wid * 32 + n * 16 + fr;
          unsigned short u = (col <= row_g) ? f2bf(v[j]) : 0;
          Abuf[((size_t)(b * NCn + ch) * Tn + row_g) * Tn + col] = u;
          rsum[m][j] += bf2f(u);
        }
      }
#pragma unroll
    for (int m = 0; m < 4; ++m)
#pragma unroll
      for (int j = 0; j < 4; ++j) {
        float r = rsum[m][j];
        r += __shfl_xor(r, 1); r += __shfl_xor(r, 2);
        r += __shfl_xor(r, 4); r += __shfl_xor(r, 8);
        if (fr == 0) rsmem[wid * 64 + m * 16 + kb * 4 + j] = r;
      }
    // exclusive chunk-prefix of zsum -> zpl
#pragma unroll
    for (int e = 0; e < 2; ++e) {
      const int c = t + e * 256;
      float s = 0.f;
      for (int ch2 = 0; ch2 < ch; ++ch2)
        s += zsum[((size_t)b * NCn + ch2) * Cn + c];
      zpl[c] = s;
    }
    __syncthreads();
    // per-row dot(PQ_row, zpl): 4 threads per row, 128 cols each
    const int row = t >> 2, q4 = (t & 3) * 128;
    const unsigned short* pq = Aq + (size_t)row * Cn + q4;
    float dacc = 0.f;
    for (int i = 0; i < 128; i += 8) {
      uint4 q = *(const uint4*)(pq + i);
      dacc += bf2f((unsigned short)(q.x & 0xffff)) * zpl[q4 + i + 0]
            + bf2f((unsigned short)(q.x >> 16))    * zpl[q4 + i + 1]
            + bf2f((unsigned short)(q.y & 0xffff)) * zpl[q4 + i + 2]
            + bf2f((unsigned short)(q.y >> 16))    * zpl[q4 + i + 3]
            + bf2f((unsigned short)(q.z & 0xffff)) * zpl[q4 + i + 4]
            + bf2f((unsigned short)(q.z >> 16))    * zpl[q4 + i + 5]
            + bf2f((unsigned short)(q.w & 0xffff)) * zpl[q4 + i + 6]
            + bf2f((unsigned short)(q.w >> 16))    * zpl[q4 + i + 7];
    }
    dacc += __shfl_xor(dacc, 1);
    dacc += __shfl_xor(dacc, 2);
    if ((t & 3) == 0)
      scale[(size_t)b * Sn + ch * Tn + i0 + row] =
          rsmem[0 * 64 + row] + rsmem[1 * 64 + row] +
          rsmem[2 * 64 + row] + rsmem[3 * 64 + row] + dacc + 1e-5f;
  }
}

// ---- stage a 128x32 bf16 tile global->LDS (256 thr), kslot ^= (row>>1)&3 ----
__device__ __forceinline__ void stage128x32(const unsigned short* __restrict__ g,
                                            int ld, unsigned short* lds,
                                            int wid, int lane) {
#pragma unroll
  for (int cc = 0; cc < 2; ++cc) {
    const int row = cc * 64 + wid * 16 + (lane >> 2);
    const int ks  = (lane & 3) ^ ((row >> 1) & 3);
    const unsigned short* src = g + (size_t)row * ld + ks * 8;
    unsigned short* dst = lds + (size_t)(cc * 256 + wid * 64) * 8;  // wave-uniform
    __builtin_amdgcn_global_load_lds(
        (const __attribute__((address_space(1))) void*)src,
        (__attribute__((address_space(3))) void*)dst, 16, 0, 0);
  }
}

// ---------------- K3: out = (A@V_c + PQ_c@Mpre_c) / scale --------------------
// Single fused 20-step pipelined K-loop (intra kt<4, inter kt>=4).
__global__ __launch_bounds__(256) void k_avinter(
    const unsigned short* __restrict__ Abuf, const unsigned short* __restrict__ Vt,
    const unsigned short* __restrict__ PQ, const unsigned short* __restrict__ Mpre,
    const float* __restrict__ scale, float* __restrict__ out)
{
  __shared__ unsigned short Al[3 * 128 * 32], Bl[3 * 128 * 32];
  const int bid = blockIdx.x;
  const int logical = (bid & 7) * 64 + (bid >> 3);
  const int d0 = (logical & 3) * 128;
  const int ch = (logical >> 2) & 15;
  const int b  = logical >> 6;
  const int t0 = ch * Tn;
  const int t = threadIdx.x, wid = t >> 6, lane = t & 63;
  const int wm = wid >> 1, wn = wid & 1;
  const int fr = lane & 15, kb = lane >> 4;
  f32x4 acc[4][4];
  const f32x4 zero = {0.f, 0.f, 0.f, 0.f};
#pragma unroll
  for (int m = 0; m < 4; ++m)
#pragma unroll
    for (int n = 0; n < 4; ++n) acc[m][n] = zero;

  const unsigned short* Aintra = Abuf + (size_t)(b * NCn + ch) * Tn * Tn;
  const unsigned short* Bintra = Vt + ((size_t)b * Cn + d0) * Sn + t0;
  const unsigned short* Ainter = PQ + ((size_t)b * Sn + t0) * Cn;
  const unsigned short* Binter = Mpre + ((size_t)(b * NCn + ch) * Cn + d0) * Cn;
  auto srcA = [&](int kt) { return (kt < 4) ? Aintra + kt * 32 : Ainter + (kt - 4) * 32; };
  auto srcB = [&](int kt) { return (kt < 4) ? Bintra + kt * 32 : Binter + (kt - 4) * 32; };
  auto ldA  = [&](int kt) { return (kt < 4) ? Tn : Cn; };
  auto ldB  = [&](int kt) { return (kt < 4) ? Sn : Cn; };
  const int nkt = (ch > 0) ? 20 : 4;

  stage128x32(srcA(0), ldA(0), Al, wid, lane);
  stage128x32(srcB(0), ldB(0), Bl, wid, lane);
  stage128x32(srcA(1), ldA(1), Al + 4096, wid, lane);
  stage128x32(srcB(1), ldB(1), Bl + 4096, wid, lane);
  int cur = 0;
  for (int kt = 0; kt < nkt; ++kt) {
    if (kt + 2 < nkt) {
      const int nx2 = (cur + 2 >= 3) ? cur - 1 : cur + 2;
      stage128x32(srcA(kt + 2), ldA(kt + 2), Al + nx2 * 4096, wid, lane);
      stage128x32(srcB(kt + 2), ldB(kt + 2), Bl + nx2 * 4096, wid, lane);
      asm volatile("s_waitcnt vmcnt(8)" ::: "memory");
    } else if (kt + 1 < nkt) {
      asm volatile("s_waitcnt vmcnt(4)" ::: "memory");
    } else {
      asm volatile("s_waitcnt vmcnt(0)" ::: "memory");
    }
    __builtin_amdgcn_s_barrier();
    asm volatile("" ::: "memory");
    const unsigned short* Ac = Al + cur * 4096;
    const unsigned short* Bc = Bl + cur * 4096;
    bf16x8 af[4], bf[4];
#pragma unroll
    for (int m = 0; m < 4; ++m) {
      const int r = wm * 64 + m * 16 + fr;
      af[m] = *(const bf16x8*)&Ac[r * 32 + ((kb ^ ((r >> 1) & 3)) << 3)];
    }
#pragma unroll
    for (int n = 0; n < 4; ++n) {
      const int r = wn * 64 + n * 16 + fr;
      bf[n] = *(const bf16x8*)&Bc[r * 32 + ((kb ^ ((r >> 1) & 3)) << 3)];
    }
    __builtin_amdgcn_s_setprio(1);
#pragma unroll
    for (int m = 0; m < 4; ++m)
#pragma unroll
      for (int n = 0; n < 4; ++n)
        acc[m][n] = __builtin_amdgcn_mfma_f32_16x16x32_bf16(af[m], bf[n], acc[m][n], 0, 0, 0);
    __builtin_amdgcn_s_setprio(0);
    __builtin_amdgcn_s_barrier();
    asm volatile("" ::: "memory");
    cur = (cur + 1 >= 3) ? 0 : cur + 1;
  }

#pragma unroll
  for (int m = 0; m < 4; ++m)
#pragma unroll
    for (int n = 0; n < 4; ++n) {
      const int row0 = t0 + wm * 64 + m * 16 + ((lane >> 4) << 2);
      const int col  = d0 + wn * 64 + n * 16 + (lane & 15);
      f32x4 v = acc[m][n];
#pragma unroll
      for (int j = 0; j < 4; ++j) {
        const size_t sidx = (size_t)b * Sn + row0 + j;
        out[sidx * Cn + col] = v[j] / scale[sidx];
      }
    }
}

// ---------------- launch -----------------------------------------------------
extern "C" void kernel_launch(void* const* d_in, const int* in_sizes, int n_in,
                              void* d_out, int out_size, void* d_ws, size_t ws_size,
                              hipStream_t stream)
{
  const float* x  = (const float*)d_in[0];
  const float* Wq = (const float*)d_in[1];
  const float* Wk = (const float*)d_in[2];
  const float* Wv = (const float*)d_in[3];
  float* out = (float*)d_out;

  unsigned short* xb   = (unsigned short*)d_ws;
  unsigned short* Wb   = xb   + (size_t)Bn * Sn * Cn;          // 8.39M
  unsigned short* PQ   = Wb   + (size_t)3 * Cn * Cn;           // 0.79M
  unsigned short* PK   = PQ   + (size_t)Bn * Sn * Cn;
  unsigned short* PKt  = PK   + (size_t)Bn * Sn * Cn;
  unsigned short* Vt   = PKt  + (size_t)Bn * Sn * Cn;
  unsigned short* Abuf = Vt   + (size_t)Bn * Sn * Cn;          // 2.10M
  unsigned short* Mpre = Abuf + (size_t)Bn * NCn * Tn * Tn;    // 33.55M
  float* scale = (float*)(Mpre + (size_t)Bn * NCn * Cn * Cn);  // 16K
  float* zsum  = scale + (size_t)Bn * Sn;                      // 64K
  (void)ws_size; (void)in_sizes; (void)n_in; (void)out_size;

  hipLaunchKernelGGL(k_cast, dim3(4096 + 384), dim3(256), 0, stream, x, Wq, Wk, Wv, xb, Wb);
  hipLaunchKernelGGL(k_proj, dim3(1536), dim3(256), 0, stream, xb, Wb, PQ, PK, PKt, Vt, zsum);
  hipLaunchKernelGGL(k_gk, dim3(768), dim3(256), 0, stream,
                     PQ, PK, zsum, Abuf, scale, PKt, Vt, Mpre);
  hipLaunchKernelGGL(k_avinter, dim3(512), dim3(256), 0, stream, Abuf, Vt, PQ, Mpre, scale, out);
}